// Round 6
// baseline (284.897 us; speedup 1.0000x reference)
//
#include <hip/hip_runtime.h>

// TwoLayerSAGE on MI355X (gfx950). Round 6.
// B=8, N=2048, IN_C=128, HID_C=256, OUT_C=32.
//
// R5 post-mortem: fusion + XCD swizzle nearly neutral (284 us); harness fill
// (~78 us @ 537 MB) + input restore dominate dur_us; of my kernels, k_prep's
// cold 134 MB A-read (4 B/lane loads) is the main remaining cost.
// R6 (low-variance):
//   - A-read widened to dwordx4 (1 KB/wave-transaction): lane owns 4 j-cols,
//     builds 4 transposed u64 column words per 64-row tile.
//   - xcat eliminated: k_fused1 reads its 32x128 x-slice from fp32 x directly.
// Structure otherwise unchanged: bits/xT prep -> fused layer-1 -> agg2+softmax,
// all XCD-swizzled (b = bx & 7).
// ws (~12 MB): W1cT | W2cT | deg_inv | bits | xT | hlT | hr

#define B_   8
#define N_   2048
#define INC  128
#define HID  256
#define OUTC 32

typedef __attribute__((ext_vector_type(8))) __bf16 bf16x8;
typedef __attribute__((ext_vector_type(4))) float f32x4;
typedef __attribute__((ext_vector_type(4))) unsigned int u32x4;
typedef __attribute__((ext_vector_type(2))) unsigned int u32x2;

__device__ __forceinline__ unsigned short f2bf(float f) {
  unsigned int u = __float_as_uint(f);
  u += 0x7FFFu + ((u >> 16) & 1u);  // round-to-nearest-even
  return (unsigned short)(u >> 16);
}

__device__ __forceinline__ f32x4 mfma16(bf16x8 a, bf16x8 b, f32x4 c) {
  return __builtin_amdgcn_mfma_f32_16x16x32_bf16(a, b, c, 0, 0, 0);
}

__device__ __forceinline__ bf16x8 ones_frag() {
  union { unsigned short u[8]; bf16x8 v; } o;
#pragma unroll
  for (int i = 0; i < 8; i++) o.u[i] = 0x3F80;
  return o.v;
}

__device__ __forceinline__ void lut_init(u32x2* lut, int t) {
  if (t < 16) {
    unsigned int w0 = (t & 1 ? 0x3F80u : 0u) | (t & 2 ? 0x3F800000u : 0u);
    unsigned int w1 = (t & 4 ? 0x3F80u : 0u) | (t & 8 ? 0x3F800000u : 0u);
    u32x2 e = {w0, w1};
    lut[t] = e;
  }
}

// nibble-LUT expansion: 8 mask bits -> bf16x8 (0.0/1.0)
__device__ __forceinline__ bf16x8 expand8(const u32x2* lut, unsigned int bval) {
  union { u32x2 u2[2]; bf16x8 v; } af;
  af.u2[0] = lut[bval & 15u];
  af.u2[1] = lut[bval >> 4];
  return af.v;
}

// ---------------------------------------------------------------------------
// Fused prep. Blocks (XCD-swizzled: batch = bx & 7 for per-batch sections):
//  [0,512):   A[b][i][j] -> bits[b][j][i/32]. Block = 256i x 256j; wave =
//             64i x 256j; lane owns 4 j-cols (dwordx4 row loads, 1 KB/wave).
//  [512,768): x fp32 -> xT[b][d][i] bf16 (LDS transpose)
//  [768,832): W1cT[e][k]: k<128 -> W1_l[k][e], else W1_r[k-128][e]
//  [832,848): W2cT[n][k]: n<32 -> W2_l[k][n], else W2_r[k][n-32]
__global__ __launch_bounds__(256, 8) void k_prep(
    const int* __restrict__ A, const float* __restrict__ x,
    const float* __restrict__ W1l, const float* __restrict__ W1r,
    const float* __restrict__ W2l, const float* __restrict__ W2r,
    unsigned int* __restrict__ bits, unsigned short* __restrict__ xT,
    unsigned short* __restrict__ W1cT, unsigned short* __restrict__ W2cT) {
  __shared__ unsigned short xls[128 * 72];
  const int bx = blockIdx.x, t = threadIdx.x;
  if (bx < 512) {
    const int w = t >> 6, l = t & 63;
    const int b = bx & 7, tile = bx >> 3;        // XCD swizzle: batch b -> XCD b
    const int ti = tile >> 3, tj = tile & 7;
    const int i0 = ti * 256 + w * 64, jc = tj * 256 + 4 * l;
    const int* Ap = A + ((size_t)(b * N_) + i0) * N_ + jc;
    unsigned long long cc0 = 0, cc1 = 0, cc2 = 0, cc3 = 0;
#pragma unroll 8
    for (int r = 0; r < 64; r++) {
      u32x4 v = *reinterpret_cast<const u32x4*>(Ap + (size_t)r * N_);
      cc0 |= (unsigned long long)(v[0] != 0u) << r;
      cc1 |= (unsigned long long)(v[1] != 0u) << r;
      cc2 |= (unsigned long long)(v[2] != 0u) << r;
      cc3 |= (unsigned long long)(v[3] != 0u) << r;
    }
    unsigned int* bp = bits + ((size_t)(b * N_) + jc) * 64 + (i0 >> 5);
    *reinterpret_cast<unsigned long long*>(bp) = cc0;
    *reinterpret_cast<unsigned long long*>(bp + 64) = cc1;
    *reinterpret_cast<unsigned long long*>(bp + 128) = cc2;
    *reinterpret_cast<unsigned long long*>(bp + 192) = cc3;
  } else if (bx < 768) {
    const int bb = bx - 512;
    const int b = bb & 7, it = bb >> 3;          // XCD swizzle
    const int i0 = it * 64;
    const int dq = (t & 31) * 4;
    const int irow = t >> 5;
#pragma unroll
    for (int s = 0; s < 8; s++) {
      int il = s * 8 + irow;
      int i = i0 + il;
      f32x4 v = *reinterpret_cast<const f32x4*>(x + ((size_t)(b * N_ + i)) * INC + dq);
      xls[(dq + 0) * 72 + il] = f2bf(v[0]);
      xls[(dq + 1) * 72 + il] = f2bf(v[1]);
      xls[(dq + 2) * 72 + il] = f2bf(v[2]);
      xls[(dq + 3) * 72 + il] = f2bf(v[3]);
    }
    __syncthreads();
    const int d = t >> 1, half = t & 1;
    const u32x4* src = reinterpret_cast<const u32x4*>(&xls[d * 72 + half * 32]);
    u32x4* dst = reinterpret_cast<u32x4*>(xT + ((size_t)(b * INC + d)) * N_ + i0 + half * 32);
#pragma unroll
    for (int q = 0; q < 4; q++) dst[q] = src[q];
  } else if (bx < 832) {
    int base = (bx - 768) * 1024 + t * 4;
#pragma unroll
    for (int q = 0; q < 4; q++) {
      int id = base + q;
      int e = id >> 8, k = id & 255;
      float v = (k < 128) ? W1l[k * 256 + e] : W1r[(k - 128) * 256 + e];
      W1cT[id] = f2bf(v);
    }
  } else {
    int base = (bx - 832) * 1024 + t * 4;
#pragma unroll
    for (int q = 0; q < 4; q++) {
      int id = base + q;
      int n = id >> 8, k = id & 255;
      float v = (n < 32) ? W2l[k * 32 + n] : W2r[k * 32 + (n - 32)];
      W2cT[id] = f2bf(v);
    }
  }
}

// ---------------------------------------------------------------------------
// Fused layer 1: agg (maskT@x, deg in-GEMM, 4-way K-split, 32j x 128d wave
// tile) -> LDS combine -> acat_s[32][264] (agg | x-direct) -> dense1 (relu,@W1)
// in LDS -> hlT = (h@W2_l)^T bf16, hr = h@W2_r + b2 fp32.
// Grid 512 (b = bx&7 -> XCD b, j0 = (bx>>3)*32), 256 thr.
__global__ __launch_bounds__(256, 2) void k_fused1(
    const unsigned int* __restrict__ bits, const unsigned short* __restrict__ xT,
    const float* __restrict__ x,
    const unsigned short* __restrict__ W1cT, const unsigned short* __restrict__ W2cT,
    const float* __restrict__ b1, const float* __restrict__ b2,
    unsigned short* __restrict__ hlT, float* __restrict__ hr,
    float* __restrict__ deg_inv) {
  __shared__ u32x2 lut[16];
  __shared__ __align__(16) float pdeg[4][2][16][4];          // 2 KB
  __shared__ __align__(16) unsigned short acat_s[32 * 264];  // 16.5 KB
  union SU {
    float part[4][6][2][64][4];    // 48 KB: [src_wave][dsi(6 non-owned)][jt][l][r]
    unsigned short hs[32 * 264];   // aliased after combine reads complete
  };
  __shared__ __align__(16) SU su;

  const int t = threadIdx.x;
  const int w = t >> 6, l = t & 63, lr = l & 15, lq = l >> 4;
  lut_init(lut, t);

  const int b = blockIdx.x & 7, j0 = (blockIdx.x >> 3) * 32;

  // early x load (cols 128..255 of acat): 32 rows x 128 cols fp32, 16 f/thread
  const int xr = t >> 3, xq = (t & 7) * 16;
  const float* xp = x + ((size_t)(b * N_ + j0 + xr)) * INC + xq;
  f32x4 xv[4];
#pragma unroll
  for (int q = 0; q < 4; q++) xv[q] = *reinterpret_cast<const f32x4*>(xp + q * 4);

  __syncthreads();  // lut ready

  const unsigned int* bp0 = bits + ((size_t)(b * N_ + j0 + lr)) * 64 + w * 16;
  const unsigned int* bp1 = bp0 + (size_t)16 * 64;  // jt=1 -> j += 16
  const unsigned short* xb = xT + (size_t)b * INC * N_ + w * 512;

  const f32x4 zero = {0.f, 0.f, 0.f, 0.f};
  f32x4 acc[2][8];
#pragma unroll
  for (int jt = 0; jt < 2; jt++)
#pragma unroll
    for (int ds = 0; ds < 8; ds++) acc[jt][ds] = zero;
  f32x4 dacc[2] = {zero, zero};
  const bf16x8 onesf = ones_frag();

  for (int s = 0; s < 16; s++) {
    bf16x8 af0 = expand8(lut, (bp0[s] >> (lq * 8)) & 0xFFu);
    bf16x8 af1 = expand8(lut, (bp1[s] >> (lq * 8)) & 0xFFu);
    dacc[0] = mfma16(af0, onesf, dacc[0]);
    dacc[1] = mfma16(af1, onesf, dacc[1]);
#pragma unroll
    for (int ds = 0; ds < 8; ds++) {
      bf16x8 bfr = *reinterpret_cast<const bf16x8*>(
          xb + ((size_t)(ds * 16 + lr)) * N_ + s * 32 + lq * 8);
      acc[0][ds] = mfma16(af0, bfr, acc[0][ds]);
      acc[1][ds] = mfma16(af1, bfr, acc[1][ds]);
    }
  }

  // ---- step 1: dump partials (6 non-owned ds chunks), pdeg, x-part -> LDS
#pragma unroll
  for (int ds = 0; ds < 8; ds++) {
    if ((ds >> 1) != w) {
      int dsi = (ds < 2 * w) ? ds : ds - 2;
#pragma unroll
      for (int jt = 0; jt < 2; jt++)
        *reinterpret_cast<f32x4*>(&su.part[w][dsi][jt][l][0]) = acc[jt][ds];
    }
  }
  if (lr == 0) {
#pragma unroll
    for (int jt = 0; jt < 2; jt++)
      *reinterpret_cast<f32x4*>(&pdeg[w][jt][lq][0]) = dacc[jt];
  }
#pragma unroll
  for (int q = 0; q < 4; q++) {
    unsigned int p0 = f2bf(xv[q][0]) | ((unsigned int)f2bf(xv[q][1]) << 16);
    unsigned int p1 = f2bf(xv[q][2]) | ((unsigned int)f2bf(xv[q][3]) << 16);
    u32x2 pk = {p0, p1};
    *reinterpret_cast<u32x2*>(&acat_s[xr * 264 + 128 + xq + q * 4]) = pk;
  }
  __syncthreads();

  // ---- step 3: combine own ds chunks {2w, 2w+1}, scale, write acat_s agg part
  float dinv2[2][4];
#pragma unroll
  for (int jt = 0; jt < 2; jt++)
#pragma unroll
    for (int r = 0; r < 4; r++) {
      float deg = pdeg[0][jt][lq][r] + pdeg[1][jt][lq][r] +
                  pdeg[2][jt][lq][r] + pdeg[3][jt][lq][r];
      dinv2[jt][r] = 1.0f / fmaxf(deg, 1.0f);
    }
  if (w < 2 && lr == 0) {
#pragma unroll
    for (int r = 0; r < 4; r++)
      deg_inv[b * N_ + j0 + w * 16 + lq * 4 + r] = dinv2[w][r];
  }
#pragma unroll
  for (int dd = 0; dd < 2; dd++) {
    int ds = 2 * w + dd;
#pragma unroll
    for (int jt = 0; jt < 2; jt++) {
      f32x4 sum = acc[jt][ds];
#pragma unroll
      for (int src = 0; src < 4; src++) {
        if (src != w) {
          int dsi = (ds < 2 * src) ? ds : ds - 2;
          f32x4 p = *reinterpret_cast<f32x4*>(&su.part[src][dsi][jt][l][0]);
          sum += p;
        }
      }
#pragma unroll
      for (int r = 0; r < 4; r++)
        acat_s[(jt * 16 + lq * 4 + r) * 264 + ds * 16 + lr] =
            f2bf(sum[r] * dinv2[jt][r]);
    }
  }
  __syncthreads();

  // ---- step 5: dense1 from LDS: h = relu(acat_s @ W1cT^T + b1) -> su.hs
  f32x4 acc2[2][4];
#pragma unroll
  for (int jt = 0; jt < 2; jt++)
#pragma unroll
    for (int es = 0; es < 4; es++) acc2[jt][es] = zero;
  const int e0 = w * 64;
#pragma unroll
  for (int ks = 0; ks < 8; ks++) {
    bf16x8 af0 = *reinterpret_cast<const bf16x8*>(&acat_s[lr * 264 + ks * 32 + lq * 8]);
    bf16x8 af1 = *reinterpret_cast<const bf16x8*>(&acat_s[(16 + lr) * 264 + ks * 32 + lq * 8]);
#pragma unroll
    for (int es = 0; es < 4; es++) {
      bf16x8 bfr = *reinterpret_cast<const bf16x8*>(
          W1cT + ((size_t)(e0 + es * 16 + lr)) * HID + ks * 32 + lq * 8);
      acc2[0][es] = mfma16(af0, bfr, acc2[0][es]);
      acc2[1][es] = mfma16(af1, bfr, acc2[1][es]);
    }
  }
  __syncthreads();  // all part reads done; su.hs may now be written
#pragma unroll
  for (int jt = 0; jt < 2; jt++)
#pragma unroll
    for (int es = 0; es < 4; es++) {
      int e = e0 + es * 16 + lr;
      float bias = b1[e];
#pragma unroll
      for (int r = 0; r < 4; r++)
        su.hs[(jt * 16 + lq * 4 + r) * 264 + e] =
            f2bf(fmaxf(acc2[jt][es][r] + bias, 0.0f));
    }
  __syncthreads();

  // ---- step 7: hlT = (h@W2_l)^T bf16 (waves 0,1); hr = h@W2_r + b2 (waves 2,3)
  const int jt = w & 1, nh = w >> 1;
  f32x4 a2[2] = {zero, zero};
#pragma unroll
  for (int ks = 0; ks < 8; ks++) {
    bf16x8 af = *reinterpret_cast<const bf16x8*>(
        &su.hs[(jt * 16 + lr) * 264 + ks * 32 + lq * 8]);
#pragma unroll
    for (int ns = 0; ns < 2; ns++) {
      bf16x8 bfr = *reinterpret_cast<const bf16x8*>(
          W2cT + ((size_t)(nh * 32 + ns * 16 + lr)) * HID + ks * 32 + lq * 8);
      a2[ns] = mfma16(af, bfr, a2[ns]);
    }
  }
  if (nh == 0) {
#pragma unroll
    for (int ns = 0; ns < 2; ns++) {
      int c = ns * 16 + lr;
      unsigned int p0 = f2bf(a2[ns][0]) | ((unsigned int)f2bf(a2[ns][1]) << 16);
      unsigned int p1 = f2bf(a2[ns][2]) | ((unsigned int)f2bf(a2[ns][3]) << 16);
      u32x2 pk = {p0, p1};
      *reinterpret_cast<u32x2*>(
          hlT + ((size_t)(b * 32 + c)) * N_ + j0 + jt * 16 + lq * 4) = pk;
    }
  } else {
#pragma unroll
    for (int ns = 0; ns < 2; ns++) {
      int c = ns * 16 + lr;
      float bias = b2[c];
#pragma unroll
      for (int r = 0; r < 4; r++)
        hr[((size_t)(b * N_ + j0 + jt * 16 + lq * 4 + r)) * OUTC + c] = a2[ns][r] + bias;
    }
  }
}

// ---------------------------------------------------------------------------
// Fused layer-2 agg + epilogue + log_softmax. Wave tile 32 j x 32 c, 4-way
// K-split, 16 KB LDS combine; waves 0,1 do the epilogue (jt = w).
// Grid 512 (b = bx&7 -> XCD b, j0 = (bx>>3)*32), 256 thr.
__global__ __launch_bounds__(256, 2) void k_agg2out(
    const unsigned int* __restrict__ bits, const unsigned short* __restrict__ hlT,
    const float* __restrict__ deg_inv, const float* __restrict__ hr,
    float* __restrict__ out) {
  __shared__ u32x2 lut[16];
  __shared__ __align__(16) float part[4][2][2][64][4];  // 16 KB
  const int t = threadIdx.x;
  const int w = t >> 6, l = t & 63, lr = l & 15, lq = l >> 4;
  lut_init(lut, t);
  __syncthreads();
  const int b = blockIdx.x & 7, j0 = (blockIdx.x >> 3) * 32;
  const unsigned int* bp0 = bits + ((size_t)(b * N_ + j0 + lr)) * 64 + w * 16;
  const unsigned int* bp1 = bp0 + (size_t)16 * 64;
  const unsigned short* hb = hlT + (size_t)b * 32 * N_ + w * 512;

  const f32x4 zero = {0.f, 0.f, 0.f, 0.f};
  f32x4 acc[2][2] = {{zero, zero}, {zero, zero}};

  for (int s = 0; s < 16; s++) {
    bf16x8 af0 = expand8(lut, (bp0[s] >> (lq * 8)) & 0xFFu);
    bf16x8 af1 = expand8(lut, (bp1[s] >> (lq * 8)) & 0xFFu);
#pragma unroll
    for (int cs = 0; cs < 2; cs++) {
      bf16x8 bfr = *reinterpret_cast<const bf16x8*>(
          hb + ((size_t)(cs * 16 + lr)) * N_ + s * 32 + lq * 8);
      acc[0][cs] = mfma16(af0, bfr, acc[0][cs]);
      acc[1][cs] = mfma16(af1, bfr, acc[1][cs]);
    }
  }
#pragma unroll
  for (int jt = 0; jt < 2; jt++)
#pragma unroll
    for (int cs = 0; cs < 2; cs++)
      *reinterpret_cast<f32x4*>(&part[w][jt][cs][l][0]) = acc[jt][cs];
  __syncthreads();
  if (w >= 2) return;

  const int jt = w;
  const size_t SZ = (size_t)B_ * N_ * OUTC;
#pragma unroll
  for (int r = 0; r < 4; r++) {
    int j = j0 + jt * 16 + lq * 4 + r;
    float dv = deg_inv[b * N_ + j];
    size_t base = ((size_t)(b * N_ + j)) * OUTC;
    float v0 = (part[0][jt][0][l][r] + part[1][jt][0][l][r] +
                part[2][jt][0][l][r] + part[3][jt][0][l][r]) * dv + hr[base + lr];
    float v1 = (part[0][jt][1][l][r] + part[1][jt][1][l][r] +
                part[2][jt][1][l][r] + part[3][jt][1][l][r]) * dv + hr[base + 16 + lr];
    float m = fmaxf(v0, v1);
#pragma unroll
    for (int d = 1; d < 16; d <<= 1) m = fmaxf(m, __shfl_xor(m, d, 64));
    float s = __expf(v0 - m) + __expf(v1 - m);
#pragma unroll
    for (int d = 1; d < 16; d <<= 1) s += __shfl_xor(s, d, 64);
    float ls = m + __logf(s);
    out[base + lr] = v0 - ls;
    out[base + 16 + lr] = v1 - ls;
    out[SZ + base + lr] = v0;
    out[SZ + base + 16 + lr] = v1;
  }
}

// ---------------------------------------------------------------------------
extern "C" void kernel_launch(void* const* d_in, const int* in_sizes, int n_in,
                              void* d_out, int out_size, void* d_ws, size_t ws_size,
                              hipStream_t stream) {
  (void)in_sizes; (void)n_in; (void)out_size; (void)ws_size;
  const float* x   = (const float*)d_in[0];
  const int*   A   = (const int*)d_in[1];
  const float* W1l = (const float*)d_in[2];
  const float* W1r = (const float*)d_in[3];
  const float* b1  = (const float*)d_in[4];
  const float* W2l = (const float*)d_in[5];
  const float* W2r = (const float*)d_in[6];
  const float* b2  = (const float*)d_in[7];
  float* out = (float*)d_out;

  char* ws = (char*)d_ws;
  unsigned short* W1cT    = (unsigned short*)(ws + 0);        // 131072
  unsigned short* W2cT    = (unsigned short*)(ws + 131072);   // -> 163840
  float*          deg_inv = (float*)(ws + 163840);            // -> 229376
  unsigned int*   bits    = (unsigned int*)(ws + 229376);     // 4 MB -> 4423680
  unsigned short* xT      = (unsigned short*)(ws + 4423680);  // 4 MB -> 8617984
  unsigned short* hlT     = (unsigned short*)(ws + 8617984);  // 1 MB -> 9666560
  float*          hr      = (float*)(ws + 9666560);           // 2 MB -> 11763712

  k_prep   <<<dim3(848), dim3(256), 0, stream>>>(A, x, W1l, W1r, W2l, W2r,
                                                 bits, xT, W1cT, W2cT);
  k_fused1 <<<dim3(512), dim3(256), 0, stream>>>(bits, xT, x, W1cT, W2cT,
                                                 b1, b2, hlT, hr, deg_inv);
  k_agg2out<<<dim3(512), dim3(256), 0, stream>>>(bits, hlT, deg_inv, hr, out);
}